// Round 8
// baseline (1698.952 us; speedup 1.0000x reference)
//
#include <hip/hip_runtime.h>

typedef unsigned int u32;
typedef unsigned short u16;
typedef float f32x4 __attribute__((ext_vector_type(4)));
typedef __bf16 bf16x8 __attribute__((ext_vector_type(8)));

#define BATCH 128
#define NIN   1024
#define DIN   256
#define NC    16
#define DC    32
#define NCOL  512

__device__ __forceinline__ float bflo(u32 v){ return __uint_as_float(v << 16); }
__device__ __forceinline__ float bfhi(u32 v){ return __uint_as_float(v & 0xffff0000u); }
__device__ __forceinline__ u32 bfround(u32 ua){ return (ua + 0x7fffu + ((ua >> 16) & 1u)) >> 16; }
__device__ __forceinline__ u32 pack2(float a, float b){
    return (bfround(__float_as_uint(a)) & 0xffffu) | (bfround(__float_as_uint(b)) << 16);
}
__device__ __forceinline__ bf16x8 ldfrag(const u16* p){
    return __builtin_bit_cast(bf16x8, *(const uint4*)p);
}

// Swizzled address (bf16 units) for a [64][256] bf16 LDS tile.
// Verified (rounds 0-6) for 16B row-chunk writes and column u16 gathers.
__device__ __forceinline__ int lds_x(int r, int d){
    int sw = (d >> 2) ^ ((r & 7) << 1) ^ (((r >> 3) & 3) << 2);
    return r * 256 + (sw << 2) + (d & 3);
}

// K0: per (b, 64-row j-chunk): xb (row-major bf16), xbT (j-contiguous B-frag
// order), s (+= col sums), Wb/WT (jc==0 blocks). Last block per b additionally
// computes the iter-0 tail (y0 from s, squash, v -> vb) using fp32 W (no race).
__global__ __launch_bounds__(256) void k_pre(const float* __restrict__ x, const float* __restrict__ W,
                                             uint4* __restrict__ xbT, u16* __restrict__ xb,
                                             float* __restrict__ s, uint2* __restrict__ Wb,
                                             uint2* __restrict__ WT, u32* __restrict__ vbw,
                                             int* __restrict__ cnt){
    __shared__ __align__(16) u16 xt[64 * 256];   // 32 KB
    __shared__ float csum[8][256];               //  8 KB (tail reuses as sl/ol)
    __shared__ int amlast;
    const int t = threadIdx.x, jc = blockIdx.x, b = blockIdx.y;

    if (jc == 0){   // W conversions: 128 (b) blocks cover all of W
        int id = b * 256 + t;
        float4 w4 = ((const float4*)W)[id];
        Wb[id] = make_uint2(pack2(w4.x, w4.y), pack2(w4.z, w4.w));
        int c = id >> 6, d4 = id & 63;           // WT[c][4*d4 .. +3]
        float e0 = W[(size_t)(d4 * 4 + 0) * NCOL + c];
        float e1 = W[(size_t)(d4 * 4 + 1) * NCOL + c];
        float e2 = W[(size_t)(d4 * 4 + 2) * NCOL + c];
        float e3 = W[(size_t)(d4 * 4 + 3) * NCOL + c];
        WT[c * 64 + d4] = make_uint2(pack2(e0, e1), pack2(e2, e3));
    }
    {   // stage 64x256: thread owns (rows r0+8m, cols d8*8..+7); 8 loads in flight
        const float4* xg = (const float4*)(x + ((size_t)b * NIN + jc * 64) * DIN);
        uint4* xbw = (uint4*)(xb + ((size_t)(b * NIN + jc * 64)) * 256);
        int d8 = t & 31, r0 = t >> 5;
        float cs[8];
        #pragma unroll
        for (int e = 0; e < 8; e++) cs[e] = 0.f;
        #pragma unroll
        for (int mb = 0; mb < 2; mb++){
            float4 va[8];
            #pragma unroll
            for (int m = 0; m < 4; m++){
                int r = r0 + 8 * (mb * 4 + m);
                va[2 * m]     = xg[r * 64 + 2 * d8];
                va[2 * m + 1] = xg[r * 64 + 2 * d8 + 1];
            }
            #pragma unroll
            for (int m = 0; m < 4; m++){
                int r = r0 + 8 * (mb * 4 + m);
                uint4 p = make_uint4(pack2(va[2*m].x, va[2*m].y),     pack2(va[2*m].z, va[2*m].w),
                                     pack2(va[2*m+1].x, va[2*m+1].y), pack2(va[2*m+1].z, va[2*m+1].w));
                *(uint4*)&xt[lds_x(r, d8 * 8)] = p;
                xbw[r * 32 + d8] = p;
                cs[0] += bflo(p.x); cs[1] += bfhi(p.x);
                cs[2] += bflo(p.y); cs[3] += bfhi(p.y);
                cs[4] += bflo(p.z); cs[5] += bfhi(p.z);
                cs[6] += bflo(p.w); cs[7] += bfhi(p.w);
            }
        }
        *(float4*)&csum[r0][d8 * 8]     = make_float4(cs[0], cs[1], cs[2], cs[3]);
        *(float4*)&csum[r0][d8 * 8 + 4] = make_float4(cs[4], cs[5], cs[6], cs[7]);
    }
    __syncthreads();
    {   // col-sum finalize -> s atomics (16 contenders per address)
        float acc = 0.f;
        #pragma unroll
        for (int r0 = 0; r0 < 8; r0++) acc += csum[r0][t];
        atomicAdd(&s[b * DIN + t], acc);
    }
    // transpose gather -> xbT (verbatim rounds 2/5/6)
    #pragma unroll
    for (int w = 0; w < 8; w++){
        int oid = t + 256 * w;                    // 0..2047
        int lane = oid & 63, js2 = (oid >> 6) & 1, dt = oid >> 7;
        int l15 = lane & 15, q = lane >> 4;
        int rb = js2 * 32 + q * 8, d = dt * 16 + l15;
        u32 r[4];
        #pragma unroll
        for (int p = 0; p < 4; p++){
            u32 lo = xt[lds_x(rb + 2 * p, d)];
            u32 hi = xt[lds_x(rb + 2 * p + 1, d)];
            r[p] = lo | (hi << 16);
        }
        xbT[(((size_t)b * 16 + dt) * 32 + (jc * 2 + js2)) * 64 + lane] = make_uint4(r[0], r[1], r[2], r[3]);
    }
    // ---- last-block-per-b: iter-0 tail ----
    __threadfence();
    __syncthreads();
    if (t == 0){
        int old = atomicAdd(&cnt[b], 1);
        amlast = (old == 15);
        __threadfence();
    }
    __syncthreads();
    if (!amlast) return;

    float* sl  = &csum[0][0];                     // 256 f32
    float* olp = &csum[2][0];                     // 512 f32
    {
        volatile const float* sv = s + b * 256;
        sl[t] = sv[t] * (1.f / 16.f);
    }
    __syncthreads();
    #pragma unroll
    for (int h = 0; h < 2; h++){
        int c = t + 256 * h;
        float a = 0.f;
        #pragma unroll 8
        for (int d = 0; d < 256; d++) a += sl[d] * W[(size_t)d * 512 + c];
        float s2 = a * a;
        s2 += __shfl_xor(s2, 1); s2 += __shfl_xor(s2, 2); s2 += __shfl_xor(s2, 4);
        s2 += __shfl_xor(s2, 8); s2 += __shfl_xor(s2, 16);
        olp[c] = a / sqrtf(s2 + 1e-7f);
    }
    __syncthreads();
    {   // v[i,d] = sum_k o[i,k] W[d,32i+k] ; fp32 W (columns 32i..32i+31 of rows 2dh,2dh+1)
        int dh = t & 127, ig = t >> 7;
        #pragma unroll
        for (int e = 0; e < 8; e++){
            int i = ig * 8 + e;
            float a0 = 0.f, a1 = 0.f;
            #pragma unroll
            for (int k4 = 0; k4 < 8; k4++){
                float4 w0 = *(const float4*)&W[(size_t)(2 * dh)     * 512 + i * 32 + 4 * k4];
                float4 w1 = *(const float4*)&W[(size_t)(2 * dh + 1) * 512 + i * 32 + 4 * k4];
                float4 o4 = *(const float4*)&olp[i * 32 + 4 * k4];
                a0 += o4.x * w0.x + o4.y * w0.y + o4.z * w0.z + o4.w * w0.w;
                a1 += o4.x * w1.x + o4.y * w1.y + o4.z * w1.z + o4.w * w1.w;
            }
            vbw[(size_t)(b * 16 + i) * 128 + dh] = pack2(a0, a1);
        }
    }
}

// K1 (one dispatch per routing iteration): per (b, 64-row j-chunk):
//   phase A: bb = v.x^T (A = vb frags, B = xb rows); softmax over i;
//   phase C: z partial = c.x (B = xbT) -> zg atomics;
//   last block per b: z = zg (volatile), re-zero zg, y = z.Wb, squash,
//   then v -> vb via WT (it<3) or write out (it==3).
__global__ __launch_bounds__(256) void k_main(const u16* __restrict__ xb, const uint4* __restrict__ xbT,
                                              u16* __restrict__ vb, const u16* __restrict__ Wb,
                                              const u32* __restrict__ WT32, float* __restrict__ zg,
                                              int* __restrict__ cnt, float* __restrict__ out, int it){
    __shared__ float bbl[16][68];                 //  4.3 KB
    __shared__ __align__(16) u16 cl[16][80];      //  2.5 KB
    __shared__ float zl[16][260];                 // 16.6 KB
    __shared__ __align__(16) float ol[512];       //  2 KB
    __shared__ int amlast;
    const int t = threadIdx.x, jc = blockIdx.x, b = blockIdx.y;
    const int lane = t & 63, wv = t >> 6;         // 4 waves
    const int l15 = lane & 15, q = lane >> 4;

    // phase A: bb[i, jloc]; wave wv owns j-tile jt = wv (16 rows)
    {
        uint4 vf[8];
        #pragma unroll
        for (int ks = 0; ks < 8; ks++)
            vf[ks] = *(const uint4*)&vb[((size_t)b * 16 + l15) * 256 + ks * 32 + q * 8];
        const u16* xr = xb + ((size_t)(b * NIN + jc * 64 + wv * 16 + l15)) * 256 + q * 8;
        f32x4 acc = {0.f, 0.f, 0.f, 0.f};
        #pragma unroll
        for (int ks = 0; ks < 8; ks++)
            acc = __builtin_amdgcn_mfma_f32_16x16x32_bf16(
                __builtin_bit_cast(bf16x8, vf[ks]), ldfrag(xr + ks * 32), acc, 0, 0, 0);
        #pragma unroll
        for (int r = 0; r < 4; r++) bbl[q * 4 + r][wv * 16 + l15] = acc[r];   // row=i, col=j
    }
    __syncthreads();

    // softmax over i per local column j (64 columns)
    if (t < 64){
        float mx = -1e30f, e[16], sum = 0.f;
        #pragma unroll
        for (int i = 0; i < 16; i++) mx = fmaxf(mx, bbl[i][t]);
        #pragma unroll
        for (int i = 0; i < 16; i++){ e[i] = __expf(bbl[i][t] - mx); sum += e[i]; }
        float inv = 1.f / sum;
        #pragma unroll
        for (int i = 0; i < 16; i++) cl[i][t] = (u16)bfround(__float_as_uint(e[i] * inv));
    }
    __syncthreads();

    // phase C: z partial — A = c frags, B = xbT (j slices js = jc*2 + ksj)
    {
        bf16x8 cf[2];
        #pragma unroll
        for (int ksj = 0; ksj < 2; ksj++) cf[ksj] = ldfrag(&cl[l15][ksj * 32 + q * 8]);
        #pragma unroll
        for (int u = 0; u < 4; u++){
            int dt = wv * 4 + u;                  // 16 d-tiles / 4 waves
            f32x4 acc = {0.f, 0.f, 0.f, 0.f};
            #pragma unroll
            for (int ksj = 0; ksj < 2; ksj++){
                uint4 bw = xbT[(((size_t)b * 16 + dt) * 32 + jc * 2 + ksj) * 64 + lane];
                acc = __builtin_amdgcn_mfma_f32_16x16x32_bf16(
                    cf[ksj], __builtin_bit_cast(bf16x8, bw), acc, 0, 0, 0);
            }
            #pragma unroll
            for (int r = 0; r < 4; r++)
                atomicAdd(&zg[((size_t)b * 16 + q * 4 + r) * 256 + dt * 16 + l15], acc[r]);
        }
    }
    // ---- last-block-per-b tail ----
    __threadfence();
    __syncthreads();
    if (t == 0){
        int old = atomicAdd(&cnt[it * 128 + b], 1);
        amlast = (old == 15);
        __threadfence();
    }
    __syncthreads();
    if (!amlast) return;

    {   // z = zg (coherent reads), and re-zero for the next dispatch
        volatile const float* zv = zg + (size_t)b * 4096;
        #pragma unroll
        for (int u0 = 0; u0 < 16; u0++){
            int idx = t + 256 * u0;
            zl[idx >> 8][idx & 255] = zv[idx];
        }
        if (it < 3){
            #pragma unroll
            for (int u0 = 0; u0 < 16; u0++) zg[(size_t)b * 4096 + t + 256 * u0] = 0.f;
        }
    }
    __syncthreads();
    #pragma unroll
    for (int h = 0; h < 2; h++){
        int c = t + 256 * h, i = c >> 5;
        float a = 0.f;
        #pragma unroll 8
        for (int d = 0; d < 256; d++) a += zl[i][d] * bflo((u32)Wb[d * 512 + c]);
        float s2 = a * a;
        s2 += __shfl_xor(s2, 1); s2 += __shfl_xor(s2, 2); s2 += __shfl_xor(s2, 4);
        s2 += __shfl_xor(s2, 8); s2 += __shfl_xor(s2, 16);
        float r = a / sqrtf(s2 + 1e-7f);
        if (it == 3) out[b * NCOL + c] = r;
        else         ol[c] = r;
    }
    if (it == 3) return;
    __syncthreads();
    {   // v-pass for the next dispatch (WT safe: produced by k_pre dispatch)
        int dh = t & 127, ig = t >> 7;
        #pragma unroll
        for (int e = 0; e < 8; e++){
            int i = ig * 8 + e;
            float a0 = 0.f, a1 = 0.f;
            #pragma unroll
            for (int k = 0; k < 32; k++){
                u32 w = WT32[(size_t)(i * 32 + k) * 128 + dh];
                float ok = ol[i * 32 + k];
                a0 += ok * bflo(w); a1 += ok * bfhi(w);
            }
            ((u32*)vb)[(size_t)(b * 16 + i) * 128 + dh] = pack2(a0, a1);
        }
    }
}

extern "C" void kernel_launch(void* const* d_in, const int* in_sizes, int n_in,
                              void* d_out, int out_size, void* d_ws, size_t ws_size,
                              hipStream_t stream){
    const float* x = (const float*)d_in[0];    // fp32 [128][1024][256]
    const float* W = (const float*)d_in[1];    // fp32 [256][512]
    float* out = (float*)d_out;                // fp32 [128][16][32]
    char* ws = (char*)d_ws;                    // ~138 MB used
    int*   cnt  = (int*)  (ws);                //      2,048 B : counters [4][128]
    float* zg   = (float*)(ws + 2048);         //  2,097,152 B : z accumulator [128][16][256]
    float* s    = (float*)(ws + 2099200);      //    131,072 B : column sums
    u16*   Wb   = (u16*)  (ws + 2230272);      //    262,144 B : W bf16 [d][c]
    u32*   WT   = (u32*)  (ws + 2492416);      //    262,144 B : W^T bf16 [c][d]
    u16*   vb   = (u16*)  (ws + 2754560);      //  1,048,576 B : v bf16
    u16*   xb   = (u16*)  (ws + 3803136);      // 67,108,864 B : x bf16 row-major
    uint4* xbT  = (uint4*)(ws + 70912000);     // 67,108,864 B : x bf16 frag order

    hipMemsetAsync(ws, 0, 2230272, stream);    // cnt + zg + s
    k_pre<<<dim3(16, BATCH), 256, 0, stream>>>(x, W, xbT, xb, s, (uint2*)Wb, (uint2*)WT,
                                               (u32*)vb, cnt);
    for (int it = 1; it < 4; it++)
        k_main<<<dim3(16, BATCH), 256, 0, stream>>>(xb, xbT, vb, Wb, WT, zg, cnt, out, it);
}